// Round 13
// baseline (203.678 us; speedup 1.0000x reference)
//
#include <hip/hip_runtime.h>
#include <hip/hip_bf16.h>

#ifndef BN_EPS
#define BN_EPS 1e-5f
#endif

// ---------------------------------------------------------------------------
// N=100000, C=64, E=1600000.
// R24: R23 with the bin path's chunk halved (4096 -> 2048) to shrink the
// fused kernel's LDS union 35.3KB -> 22.7KB.
//   R23 post-mortem: fused pre(bin||proj) = 49us at 23% occupancy -- the
//   union LDS (35KB, sized by the bin path) capped co-residency at 4
//   blocks/CU, starving the proj blocks' latency hiding. CHUNK=2048 gives
//   lout 8K + lb 4K + h2 4K + cursors 6.3K = 22.7KB -> 7 blocks/CU
//   (VGPR 68 -> 7 waves/SIMD, consistent). Bin blocks double (782), same
//   total work. Everything else byte-identical to R23 (186.2us, passed).
// 5 dispatches: memset(cnt2+stats_p), pre(bin||proj), csr(+scale),
// agg(+stats), bn. bias cancels inside BatchNorm, skipped.
// ---------------------------------------------------------------------------

#define CAP2 3072   // per-sub-bucket slack capacity (mean 2049, sigma 45)
#define CHUNK 2048  // bin-path edges per block

__device__ __forceinline__ unsigned short f2bf(float f) {
    unsigned u = __float_as_uint(f);
    u += 0x7FFF + ((u >> 16) & 1);  // round-to-nearest-even
    return (unsigned short)(u >> 16);
}
__device__ __forceinline__ float bf2f(unsigned v) {
    return __uint_as_float(v << 16);
}

// Blocks [0, EB): direct 782-bucket binning (CHUNK=2048).
// Blocks [EB, EB+PB): 64-row projection tiles y' = bf16(x@W).
// LDS union: bin 22.7KB, proj 8.2KB -> 7 blocks/CU.
// Block 0 also zeroes the y zero row.
__global__ __launch_bounds__(256) void k_pre(const int* __restrict__ src,
                                             const int* __restrict__ dst,
                                             const float* __restrict__ x,
                                             const float* __restrict__ W,
                                             int* __restrict__ cnt2,
                                             unsigned* __restrict__ binned,
                                             unsigned short* __restrict__ yb,
                                             unsigned* __restrict__ ybz,
                                             int E, int SUB, int EB, int N) {
    __shared__ __align__(16) char smem[22656];
    int tid = threadIdx.x;
    int bid = blockIdx.x;
    if (bid == 0) {
        if (tid < 32) ybz[tid] = 0u;
    }
    if (bid >= EB) {
        // ---- projection path: y'[n] = bf16(x[n] @ W), 64-row tile ----
        unsigned* tile = (unsigned*)smem;  // 64*32 u32 = 8KB
        int lane = tid & 63;
        int w = tid >> 6;
        int r0 = (bid - EB) * 64;
        const float4* gp = (const float4*)(x + (size_t)r0 * 64);
#pragma unroll
        for (int i = 0; i < 4; i++) {
            int idx = tid + 256 * i;        // row = idx>>4, c4 = idx&15
            int n = r0 + (idx >> 4);
            float4 v = {0.f, 0.f, 0.f, 0.f};
            if (n < N) v = gp[idx];
            unsigned lo = (unsigned)f2bf(v.x) | ((unsigned)f2bf(v.y) << 16);
            unsigned hi = (unsigned)f2bf(v.z) | ((unsigned)f2bf(v.w) << 16);
            tile[(idx >> 4) * 32 + (idx & 15) * 2] = lo;
            tile[(idx >> 4) * 32 + (idx & 15) * 2 + 1] = hi;
        }
        float wcol[64];
#pragma unroll
        for (int k = 0; k < 64; k++) wcol[k] = W[k * 64 + lane];
        __syncthreads();
#pragma unroll
        for (int rr = 0; rr < 16; rr += 2) {
            int lr0 = w * 16 + rr;
            int n0 = r0 + lr0;
            if (n0 >= N) break;
            const unsigned* row0 = tile + lr0 * 32;
            const unsigned* row1 = row0 + 32;
            float o0 = 0.f, o1 = 0.f;
#pragma unroll
            for (int kp = 0; kp < 32; kp++) {
                unsigned u0 = row0[kp], u1 = row1[kp];
                o0 = fmaf(bf2f(u0 & 0xFFFFu), wcol[2 * kp], o0);
                o0 = fmaf(bf2f(u0 >> 16), wcol[2 * kp + 1], o0);
                o1 = fmaf(bf2f(u1 & 0xFFFFu), wcol[2 * kp], o1);
                o1 = fmaf(bf2f(u1 >> 16), wcol[2 * kp + 1], o1);
            }
            yb[(size_t)n0 * 64 + lane] = f2bf(o0);
            if (n0 + 1 < N) yb[(size_t)(n0 + 1) * 64 + lane] = f2bf(o1);
        }
        return;
    }
    // ---- binning path (R15 body, CHUNK=2048) ----
    int* h2 = (int*)smem;                              // 1024 ints
    int* gbase = (int*)(smem + 4096);                  // 784
    int* hcur = (int*)(smem + 7232);                   // 784
    unsigned* lout = (unsigned*)(smem + 10368);        // 2048 u32
    unsigned short* lb = (unsigned short*)(smem + 18560);  // 2048 u16
    int c0 = bid * CHUNK;
    if (c0 >= E) return;
    int cnt = min(CHUNK, E - c0);
    for (int i = tid; i < 1024; i += 256) h2[i] = 0;
    __syncthreads();
    for (int i = tid; i < cnt; i += 256)
        atomicAdd(&h2[dst[c0 + i] >> 7], 1);
    __syncthreads();
    // inclusive scan of h2[0..1024) with 256 threads (read-all/write-all)
    for (int off = 1; off < 1024; off <<= 1) {
        int t0 = tid, t1 = tid + 256, t2 = tid + 512, t3 = tid + 768;
        int a0 = (t0 >= off) ? h2[t0 - off] : 0;
        int a1 = (t1 >= off) ? h2[t1 - off] : 0;
        int a2 = (t2 >= off) ? h2[t2 - off] : 0;
        int a3 = (t3 >= off) ? h2[t3 - off] : 0;
        __syncthreads();
        h2[t0] += a0; h2[t1] += a1; h2[t2] += a2; h2[t3] += a3;
        __syncthreads();
    }
    // reserve global space per nonempty sub-bucket; init local cursors
    for (int s2 = tid; s2 < SUB; s2 += 256) {
        int prev = s2 ? h2[s2 - 1] : 0;
        int v = h2[s2] - prev;
        hcur[s2] = prev;
        if (v > 0) gbase[s2] = atomicAdd(&cnt2[s2], v);
    }
    __syncthreads();
    // pack into LDS grouped by sub-bucket
    for (int i = tid; i < cnt; i += 256) {
        int d = dst[c0 + i];
        int s = src[c0 + i];
        int sb = d >> 7;
        unsigned packed = (unsigned)s | ((unsigned)(d & 127) << 17);
        int p = atomicAdd(&hcur[sb], 1);
        lout[p] = packed;
        lb[p] = (unsigned short)sb;
    }
    __syncthreads();
    // grouped flush: run for sub-bucket sb sits at [excl, excl+v) in lout
    for (int i = tid; i < cnt; i += 256) {
        int sb = lb[i];
        int hx = sb ? h2[sb - 1] : 0;  // local exclusive base
        binned[(size_t)sb * CAP2 + gbase[sb] + (i - hx)] = lout[i];
    }
}

// One block per 128-node sub-bucket: stage window in LDS, LDS histogram ->
// deg/dinv/offs, scatter csr IN PLACE, then scale this block's 128 y' rows
// in place: y[n] = bf16(dinv[n] * y'[n]).
__global__ __launch_bounds__(256) void k_csr(const int* __restrict__ cnt2,
                                             unsigned* __restrict__ binned,
                                             int* __restrict__ deg,
                                             float* __restrict__ dinv,
                                             int* __restrict__ offs,
                                             unsigned* __restrict__ ybw,
                                             int N) {
    __shared__ int hist[128], lbase[128], lcur[128];
    __shared__ float sdv[128];
    __shared__ unsigned win[CAP2];
    int s = blockIdx.x;
    int tid = threadIdx.x;
    int cnt = cnt2[s];
    unsigned* bb = binned + (size_t)s * CAP2;
    for (int j = tid; j < cnt; j += 256) win[j] = bb[j];
    if (tid < 128) { hist[tid] = 0; lcur[tid] = 0; }
    __syncthreads();
    for (int j = tid; j < cnt; j += 256)
        atomicAdd(&hist[win[j] >> 17], 1);
    __syncthreads();
    if (tid == 0) {
        int acc = 0;
        for (int k = 0; k < 128; k++) { lbase[k] = acc; acc += hist[k]; }
    }
    __syncthreads();
    if (tid < 128) {  // deg / dinv / offs for this sub-bucket's 128 nodes
        int n = (s << 7) + tid;
        float dn = rsqrtf((float)(hist[tid] + 1));  // +1 = self-loop
        sdv[tid] = dn;
        if (n < N) {
            deg[n] = hist[tid];
            dinv[n] = dn;
            offs[n] = s * CAP2 + lbase[tid];
        }
    }
    __syncthreads();
    // in-place scatter: reads fully staged in win, writes node-ordered
    for (int j = tid; j < cnt; j += 256) {
        unsigned e = win[j];
        int ld = e >> 17;
        bb[lbase[ld] + atomicAdd(&lcur[ld], 1)] = e & 0x1FFFFu;
    }
    // scale this block's 128 rows in place: y = bf16(dinv * y')
    unsigned* yrow = ybw + (size_t)(s << 7) * 32;
    for (int i = tid; i < 4096; i += 256) {
        int n = (s << 7) + (i >> 5);
        if (n < N) {
            float dn = sdv[i >> 5];
            unsigned u = yrow[i];
            unsigned lo = f2bf(bf2f(u & 0xFFFFu) * dn);
            unsigned hi = f2bf(bf2f(u >> 16) * dn);
            yrow[i] = lo | (hi << 16);
        }
    }
}

// Wave per node, aggregation in y-space (R15 body). BN stats fused with
// 64-way-spread atomics (R21 proven).
__global__ __launch_bounds__(256) void k_agg(const int* __restrict__ offs,
                                             const int* __restrict__ deg,
                                             const int* __restrict__ csr,
                                             const unsigned short* __restrict__ yb,
                                             const float* __restrict__ dinv,
                                             unsigned* __restrict__ yagg,
                                             float* __restrict__ stats_p, int N) {
    __shared__ float red[512];  // [4: psx psy pqx pqy][4 waves][32 p]
    int tid = threadIdx.x;
    int lane = tid & 63;
    int p = lane & 31;   // channel pair (channels 2p, 2p+1)
    int h = lane >> 5;   // half: which edge of a pair this lane gathers
    int w = tid >> 6;
    int wid = (blockIdx.x * 256 + tid) >> 6;
    int nw = (gridDim.x * 256) >> 6;
    const unsigned* xw = (const unsigned*)yb;

    float psx = 0.f, psy = 0.f, pqx = 0.f, pqy = 0.f;
    for (int n = wid; n < N; n += nw) {
        float dn = dinv[n];
        unsigned sv = xw[(size_t)n * 32 + p];  // self row (pre-scaled)
        float accx = (h == 0) ? bf2f(sv & 0xFFFFu) : 0.f;
        float accy = (h == 0) ? bf2f(sv >> 16) : 0.f;
        int j0 = offs[n];
        int j1 = j0 + deg[n];
        for (int jb = j0; jb < j1; jb += 64) {
            int cnt = min(64, j1 - jb);
            int idx = N;  // zero row for overshoot lanes
            if (lane < cnt) idx = csr[jb + lane];
            for (int j = 0; j < cnt; j += 16) {
                int s0 = __shfl(idx, j + 0 + h),  s1 = __shfl(idx, j + 2 + h);
                int s2 = __shfl(idx, j + 4 + h),  s3 = __shfl(idx, j + 6 + h);
                int s4 = __shfl(idx, j + 8 + h),  s5 = __shfl(idx, j + 10 + h);
                int s6 = __shfl(idx, j + 12 + h), s7 = __shfl(idx, j + 14 + h);
                unsigned v0 = xw[(size_t)s0 * 32 + p];
                unsigned v1 = xw[(size_t)s1 * 32 + p];
                unsigned v2 = xw[(size_t)s2 * 32 + p];
                unsigned v3 = xw[(size_t)s3 * 32 + p];
                unsigned v4 = xw[(size_t)s4 * 32 + p];
                unsigned v5 = xw[(size_t)s5 * 32 + p];
                unsigned v6 = xw[(size_t)s6 * 32 + p];
                unsigned v7 = xw[(size_t)s7 * 32 + p];
                accx += bf2f(v0 & 0xFFFFu); accy += bf2f(v0 >> 16);
                accx += bf2f(v1 & 0xFFFFu); accy += bf2f(v1 >> 16);
                accx += bf2f(v2 & 0xFFFFu); accy += bf2f(v2 >> 16);
                accx += bf2f(v3 & 0xFFFFu); accy += bf2f(v3 >> 16);
                accx += bf2f(v4 & 0xFFFFu); accy += bf2f(v4 >> 16);
                accx += bf2f(v5 & 0xFFFFu); accy += bf2f(v5 >> 16);
                accx += bf2f(v6 & 0xFFFFu); accy += bf2f(v6 >> 16);
                accx += bf2f(v7 & 0xFFFFu); accy += bf2f(v7 >> 16);
            }
        }
        accx += __shfl_xor(accx, 32);
        accy += __shfl_xor(accy, 32);
        float ox = accx * dn, oy = accy * dn;  // pre-BN outputs
        if (h == 0) {
            unsigned o = (unsigned)f2bf(ox) | ((unsigned)f2bf(oy) << 16);
            yagg[(size_t)n * 32 + p] = o;
            psx += ox; pqx = fmaf(ox, ox, pqx);
            psy += oy; pqy = fmaf(oy, oy, pqy);
        }
    }
    // block reduce (h==0 lanes carry the values)
    if (h == 0) {
        red[w * 32 + p] = psx;
        red[128 + w * 32 + p] = psy;
        red[256 + w * 32 + p] = pqx;
        red[384 + w * 32 + p] = pqy;
    }
    __syncthreads();
    float* sp = stats_p + (blockIdx.x & 63) * 128;
    if (tid < 64) {        // channel c = tid: sum
        int c = tid, pp = c >> 1, odd = c & 1;
        float* b = red + odd * 128;
        atomicAdd(&sp[c], b[pp] + b[32 + pp] + b[64 + pp] + b[96 + pp]);
    } else if (tid < 128) {  // channel c: sumsq
        int c = tid - 64, pp = c >> 1, odd = c & 1;
        float* b = red + 256 + odd * 128;
        atomicAdd(&sp[64 + c], b[pp] + b[32 + pp] + b[64 + pp] + b[96 + pp]);
    }
}

// Elementwise BN+ReLU apply. Prologue: reduce stats_p[64][128] (32KB,
// L2-hot) -> bnprep scale/shift.
__global__ __launch_bounds__(256) void k_bn(const unsigned* __restrict__ yagg,
                                            const float* __restrict__ stats_p,
                                            const float* __restrict__ gamma,
                                            const float* __restrict__ beta,
                                            float* __restrict__ out, int N,
                                            float invN) {
    __shared__ float ssl[128];
    int t = threadIdx.x;
    if (t < 64) {
        float s = 0.f, q = 0.f;
        for (int j = 0; j < 64; j++) {
            s += stats_p[j * 128 + t];
            q += stats_p[j * 128 + 64 + t];
        }
        float mean = s * invN;
        float var = q * invN - mean * mean;  // biased var
        float sc = gamma[t] * rsqrtf(var + BN_EPS);
        ssl[t] = sc;
        ssl[64 + t] = beta[t] - mean * sc;
    }
    __syncthreads();
    int total = N * 32;
    for (int i = blockIdx.x * 256 + t; i < total; i += gridDim.x * 256) {
        unsigned u = yagg[i];
        int p = i & 31;
        float2 o;
        o.x = fmaxf(fmaf(bf2f(u & 0xFFFFu), ssl[2 * p], ssl[64 + 2 * p]), 0.f);
        o.y = fmaxf(fmaf(bf2f(u >> 16), ssl[2 * p + 1], ssl[64 + 2 * p + 1]), 0.f);
        ((float2*)out)[i] = o;
    }
}

extern "C" void kernel_launch(void* const* d_in, const int* in_sizes, int n_in,
                              void* d_out, int out_size, void* d_ws, size_t ws_size,
                              hipStream_t stream) {
    const float* x = (const float*)d_in[0];
    const int* ei = (const int*)d_in[1];
    const float* W = (const float*)d_in[2];
    // d_in[3] = bias: cancels inside BatchNorm, unused.
    const float* gamma = (const float*)d_in[4];
    const float* beta = (const float*)d_in[5];
    float* out = (float*)d_out;

    const int N = in_sizes[0] / 64;
    const int E = in_sizes[1] / 2;
    const int* src = ei;
    const int* dst = ei + E;
    const int SUB = (N + 127) >> 7;        // 782 sub-buckets of 128 nodes
    // Per-sub-bucket count ~ Binomial(E, 128/N): mean 2049, sigma 45.
    // CAP2=3072 = mean + 22.6 sigma -> overflow impossible.

    char* ws = (char*)d_ws;
    size_t o = 0;
    int* cnt2 = (int*)(ws + o); o += 4096;         // SUB ints
    float* stats_p = (float*)(ws + o); o += 32768; // [64][128] partials
    // one memset covers cnt2 + stats_p (contiguous 36864 B)
    int* deg = (int*)(ws + o); o += (size_t)4 * N;
    int* offs = (int*)(ws + o); o += (size_t)4 * N;
    float* dinv = (float*)(ws + o); o += (size_t)4 * N;
    unsigned short* yb = (unsigned short*)(ws + o); o += (size_t)128 * (N + 1);
    unsigned* yagg = (unsigned*)(ws + o); o += (size_t)128 * N;
    unsigned* binned = (unsigned*)(ws + o); o += (size_t)4 * SUB * CAP2;
    // csr aliases binned: k_csr scatters in place (window staged in LDS).

    hipMemsetAsync(ws, 0, 36864, stream);

    const int EB = (E + CHUNK - 1) / CHUNK;  // 782 binning blocks
    const int PB = (N + 63) / 64;            // 1563 projection blocks
    k_pre<<<EB + PB, 256, 0, stream>>>(src, dst, x, W, cnt2, binned, yb,
                                       (unsigned*)(yb + (size_t)N * 64),
                                       E, SUB, EB, N);
    k_csr<<<SUB, 256, 0, stream>>>(cnt2, binned, deg, dinv, offs,
                                   (unsigned*)yb, N);
    k_agg<<<2048, 256, 0, stream>>>(offs, deg, (const int*)binned, yb, dinv,
                                    yagg, stats_p, N);
    k_bn<<<1024, 256, 0, stream>>>(yagg, stats_p, gamma, beta, out, N,
                                   1.0f / (float)N);
}

// Round 14
// 183.217 us; speedup vs baseline: 1.1117x; 1.1117x over previous
//
#include <hip/hip_runtime.h>
#include <hip/hip_bf16.h>

#ifndef BN_EPS
#define BN_EPS 1e-5f
#endif

// ---------------------------------------------------------------------------
// N=100000, C=64, E=1600000.
// R25: R23 (CHUNK=4096 restored) + VGPR/LDS dual fix in the fused pre kernel.
//   R24 post-mortem: occupancy was VGPR-capped (68 > the 64 cliff), not
//   LDS-capped; halved CHUNK only added scan overhead + write fragmentation.
//   Fix (a): proj path keeps W in LDS as float2 pairs (16KB, f32-exact) ->
//   VGPR ~45 (under the next cliff, 6 waves/SIMD OK).
//   Fix (b): bin path drops lb[4096] (8KB): bucket of lout[i] is recovered
//   from the h2 inclusive scan; lout's free top byte stores sb&255 as a
//   hint; <=4 candidates (hint+256k) checked against h2 ranges.
//   Union LDS 26752B -> 6 blocks/CU (24 waves/CU, was 16).
//   k_csr / k_agg / k_bn byte-identical to R23 (186.2us, passed).
// 5 dispatches: memset(cnt2+stats_p), pre(bin||proj), csr(+scale),
// agg(+stats), bn. bias cancels inside BatchNorm, skipped.
// ---------------------------------------------------------------------------

#define CAP2 3072  // per-sub-bucket slack capacity (mean 2049, sigma 45)

__device__ __forceinline__ unsigned short f2bf(float f) {
    unsigned u = __float_as_uint(f);
    u += 0x7FFF + ((u >> 16) & 1);  // round-to-nearest-even
    return (unsigned short)(u >> 16);
}
__device__ __forceinline__ float bf2f(unsigned v) {
    return __uint_as_float(v << 16);
}

// Blocks [0, EB): direct 782-bucket binning (CHUNK=4096, no lb array).
// Blocks [EB, EB+PB): 64-row projection tiles y' = bf16(x@W), W in LDS f2.
// LDS union: bin 26752B, proj 24576B -> 6 blocks/CU.
// Block 0 also zeroes the y zero row.
__global__ __launch_bounds__(256) void k_pre(const int* __restrict__ src,
                                             const int* __restrict__ dst,
                                             const float* __restrict__ x,
                                             const float* __restrict__ W,
                                             int* __restrict__ cnt2,
                                             unsigned* __restrict__ binned,
                                             unsigned short* __restrict__ yb,
                                             unsigned* __restrict__ ybz,
                                             int E, int SUB, int EB, int N) {
    __shared__ __align__(16) char smem[26752];
    int tid = threadIdx.x;
    int bid = blockIdx.x;
    if (bid == 0) {
        if (tid < 32) ybz[tid] = 0u;
    }
    if (bid >= EB) {
        // ---- projection path: y'[n] = bf16(x[n] @ W), 64-row tile ----
        unsigned* tile = (unsigned*)smem;            // 64*32 u32 = 8KB
        float2* Wp = (float2*)(smem + 8192);         // [32][64] f2 = 16KB
        int lane = tid & 63;
        int w = tid >> 6;
        int r0 = (bid - EB) * 64;
        const float4* gp = (const float4*)(x + (size_t)r0 * 64);
#pragma unroll
        for (int i = 0; i < 4; i++) {
            int idx = tid + 256 * i;        // row = idx>>4, c4 = idx&15
            int n = r0 + (idx >> 4);
            float4 v = {0.f, 0.f, 0.f, 0.f};
            if (n < N) v = gp[idx];
            unsigned lo = (unsigned)f2bf(v.x) | ((unsigned)f2bf(v.y) << 16);
            unsigned hi = (unsigned)f2bf(v.z) | ((unsigned)f2bf(v.w) << 16);
            tile[(idx >> 4) * 32 + (idx & 15) * 2] = lo;
            tile[(idx >> 4) * 32 + (idx & 15) * 2 + 1] = hi;
        }
        // stage W as (even-k, odd-k) pairs: Wp[kp*64+c] = (W[2kp][c], W[2kp+1][c])
#pragma unroll
        for (int i = 0; i < 8; i++) {
            int idx = tid + 256 * i;        // kp = idx>>6, c = idx&63
            int kp = idx >> 6, c = idx & 63;
            float2 w2;
            w2.x = W[(2 * kp) * 64 + c];
            w2.y = W[(2 * kp + 1) * 64 + c];
            Wp[idx] = w2;
        }
        __syncthreads();
#pragma unroll
        for (int rr = 0; rr < 16; rr += 2) {
            int lr0 = w * 16 + rr;
            int n0 = r0 + lr0;
            if (n0 >= N) break;
            const unsigned* row0 = tile + lr0 * 32;
            const unsigned* row1 = row0 + 32;
            float o0 = 0.f, o1 = 0.f;
#pragma unroll
            for (int kp = 0; kp < 32; kp++) {
                unsigned u0 = row0[kp], u1 = row1[kp];
                float2 w2 = Wp[kp * 64 + lane];
                o0 = fmaf(bf2f(u0 & 0xFFFFu), w2.x, o0);
                o0 = fmaf(bf2f(u0 >> 16), w2.y, o0);
                o1 = fmaf(bf2f(u1 & 0xFFFFu), w2.x, o1);
                o1 = fmaf(bf2f(u1 >> 16), w2.y, o1);
            }
            yb[(size_t)n0 * 64 + lane] = f2bf(o0);
            if (n0 + 1 < N) yb[(size_t)(n0 + 1) * 64 + lane] = f2bf(o1);
        }
        return;
    }
    // ---- binning path (R15 body, CHUNK=4096, lb removed) ----
    int* h2 = (int*)smem;                              // 1024 ints
    int* gbase = (int*)(smem + 4096);                  // 784
    int* hcur = (int*)(smem + 7232);                   // 784
    unsigned* lout = (unsigned*)(smem + 10368);        // 4096 u32 -> end 26752
    int c0 = bid * 4096;
    if (c0 >= E) return;
    int cnt = min(4096, E - c0);
    for (int i = tid; i < 1024; i += 256) h2[i] = 0;
    __syncthreads();
    for (int i = tid; i < cnt; i += 256)
        atomicAdd(&h2[dst[c0 + i] >> 7], 1);
    __syncthreads();
    // inclusive scan of h2[0..1024) with 256 threads (read-all/write-all)
    for (int off = 1; off < 1024; off <<= 1) {
        int t0 = tid, t1 = tid + 256, t2 = tid + 512, t3 = tid + 768;
        int a0 = (t0 >= off) ? h2[t0 - off] : 0;
        int a1 = (t1 >= off) ? h2[t1 - off] : 0;
        int a2 = (t2 >= off) ? h2[t2 - off] : 0;
        int a3 = (t3 >= off) ? h2[t3 - off] : 0;
        __syncthreads();
        h2[t0] += a0; h2[t1] += a1; h2[t2] += a2; h2[t3] += a3;
        __syncthreads();
    }
    // reserve global space per nonempty sub-bucket; init local cursors
    for (int s2 = tid; s2 < SUB; s2 += 256) {
        int prev = s2 ? h2[s2 - 1] : 0;
        int v = h2[s2] - prev;
        hcur[s2] = prev;
        if (v > 0) gbase[s2] = atomicAdd(&cnt2[s2], v);
    }
    __syncthreads();
    // pack into LDS grouped by sub-bucket; top byte = sb low 8 bits (hint)
    for (int i = tid; i < cnt; i += 256) {
        int d = dst[c0 + i];
        int s = src[c0 + i];
        int sb = d >> 7;
        unsigned packed = (unsigned)s | ((unsigned)(d & 127) << 17) |
                          ((unsigned)(sb & 255) << 24);
        int p = atomicAdd(&hcur[sb], 1);
        lout[p] = packed;
    }
    __syncthreads();
    // grouped flush: bucket of position i recovered from h2 ranges using the
    // hint -- candidates are hint+256k (<=4, exactly one contains i).
    for (int i = tid; i < cnt; i += 256) {
        unsigned v = lout[i];
        int sb = v >> 24;  // start at hint
        int hx = 0;
        for (; sb < SUB; sb += 256) {
            int lo = sb ? h2[sb - 1] : 0;
            if (i >= lo && i < h2[sb]) { hx = lo; break; }
        }
        binned[(size_t)sb * CAP2 + gbase[sb] + (i - hx)] = v & 0xFFFFFFu;
    }
}

// One block per 128-node sub-bucket: stage window in LDS, LDS histogram ->
// deg/dinv/offs, scatter csr IN PLACE, then scale this block's 128 y' rows
// in place: y[n] = bf16(dinv[n] * y'[n]).
__global__ __launch_bounds__(256) void k_csr(const int* __restrict__ cnt2,
                                             unsigned* __restrict__ binned,
                                             int* __restrict__ deg,
                                             float* __restrict__ dinv,
                                             int* __restrict__ offs,
                                             unsigned* __restrict__ ybw,
                                             int N) {
    __shared__ int hist[128], lbase[128], lcur[128];
    __shared__ float sdv[128];
    __shared__ unsigned win[CAP2];
    int s = blockIdx.x;
    int tid = threadIdx.x;
    int cnt = cnt2[s];
    unsigned* bb = binned + (size_t)s * CAP2;
    for (int j = tid; j < cnt; j += 256) win[j] = bb[j];
    if (tid < 128) { hist[tid] = 0; lcur[tid] = 0; }
    __syncthreads();
    for (int j = tid; j < cnt; j += 256)
        atomicAdd(&hist[win[j] >> 17], 1);
    __syncthreads();
    if (tid == 0) {
        int acc = 0;
        for (int k = 0; k < 128; k++) { lbase[k] = acc; acc += hist[k]; }
    }
    __syncthreads();
    if (tid < 128) {  // deg / dinv / offs for this sub-bucket's 128 nodes
        int n = (s << 7) + tid;
        float dn = rsqrtf((float)(hist[tid] + 1));  // +1 = self-loop
        sdv[tid] = dn;
        if (n < N) {
            deg[n] = hist[tid];
            dinv[n] = dn;
            offs[n] = s * CAP2 + lbase[tid];
        }
    }
    __syncthreads();
    // in-place scatter: reads fully staged in win, writes node-ordered
    for (int j = tid; j < cnt; j += 256) {
        unsigned e = win[j];
        int ld = e >> 17;
        bb[lbase[ld] + atomicAdd(&lcur[ld], 1)] = e & 0x1FFFFu;
    }
    // scale this block's 128 rows in place: y = bf16(dinv * y')
    unsigned* yrow = ybw + (size_t)(s << 7) * 32;
    for (int i = tid; i < 4096; i += 256) {
        int n = (s << 7) + (i >> 5);
        if (n < N) {
            float dn = sdv[i >> 5];
            unsigned u = yrow[i];
            unsigned lo = f2bf(bf2f(u & 0xFFFFu) * dn);
            unsigned hi = f2bf(bf2f(u >> 16) * dn);
            yrow[i] = lo | (hi << 16);
        }
    }
}

// Wave per node, aggregation in y-space (R15 body). BN stats fused with
// 64-way-spread atomics (R21 proven).
__global__ __launch_bounds__(256) void k_agg(const int* __restrict__ offs,
                                             const int* __restrict__ deg,
                                             const int* __restrict__ csr,
                                             const unsigned short* __restrict__ yb,
                                             const float* __restrict__ dinv,
                                             unsigned* __restrict__ yagg,
                                             float* __restrict__ stats_p, int N) {
    __shared__ float red[512];  // [4: psx psy pqx pqy][4 waves][32 p]
    int tid = threadIdx.x;
    int lane = tid & 63;
    int p = lane & 31;   // channel pair (channels 2p, 2p+1)
    int h = lane >> 5;   // half: which edge of a pair this lane gathers
    int w = tid >> 6;
    int wid = (blockIdx.x * 256 + tid) >> 6;
    int nw = (gridDim.x * 256) >> 6;
    const unsigned* xw = (const unsigned*)yb;

    float psx = 0.f, psy = 0.f, pqx = 0.f, pqy = 0.f;
    for (int n = wid; n < N; n += nw) {
        float dn = dinv[n];
        unsigned sv = xw[(size_t)n * 32 + p];  // self row (pre-scaled)
        float accx = (h == 0) ? bf2f(sv & 0xFFFFu) : 0.f;
        float accy = (h == 0) ? bf2f(sv >> 16) : 0.f;
        int j0 = offs[n];
        int j1 = j0 + deg[n];
        for (int jb = j0; jb < j1; jb += 64) {
            int cnt = min(64, j1 - jb);
            int idx = N;  // zero row for overshoot lanes
            if (lane < cnt) idx = csr[jb + lane];
            for (int j = 0; j < cnt; j += 16) {
                int s0 = __shfl(idx, j + 0 + h),  s1 = __shfl(idx, j + 2 + h);
                int s2 = __shfl(idx, j + 4 + h),  s3 = __shfl(idx, j + 6 + h);
                int s4 = __shfl(idx, j + 8 + h),  s5 = __shfl(idx, j + 10 + h);
                int s6 = __shfl(idx, j + 12 + h), s7 = __shfl(idx, j + 14 + h);
                unsigned v0 = xw[(size_t)s0 * 32 + p];
                unsigned v1 = xw[(size_t)s1 * 32 + p];
                unsigned v2 = xw[(size_t)s2 * 32 + p];
                unsigned v3 = xw[(size_t)s3 * 32 + p];
                unsigned v4 = xw[(size_t)s4 * 32 + p];
                unsigned v5 = xw[(size_t)s5 * 32 + p];
                unsigned v6 = xw[(size_t)s6 * 32 + p];
                unsigned v7 = xw[(size_t)s7 * 32 + p];
                accx += bf2f(v0 & 0xFFFFu); accy += bf2f(v0 >> 16);
                accx += bf2f(v1 & 0xFFFFu); accy += bf2f(v1 >> 16);
                accx += bf2f(v2 & 0xFFFFu); accy += bf2f(v2 >> 16);
                accx += bf2f(v3 & 0xFFFFu); accy += bf2f(v3 >> 16);
                accx += bf2f(v4 & 0xFFFFu); accy += bf2f(v4 >> 16);
                accx += bf2f(v5 & 0xFFFFu); accy += bf2f(v5 >> 16);
                accx += bf2f(v6 & 0xFFFFu); accy += bf2f(v6 >> 16);
                accx += bf2f(v7 & 0xFFFFu); accy += bf2f(v7 >> 16);
            }
        }
        accx += __shfl_xor(accx, 32);
        accy += __shfl_xor(accy, 32);
        float ox = accx * dn, oy = accy * dn;  // pre-BN outputs
        if (h == 0) {
            unsigned o = (unsigned)f2bf(ox) | ((unsigned)f2bf(oy) << 16);
            yagg[(size_t)n * 32 + p] = o;
            psx += ox; pqx = fmaf(ox, ox, pqx);
            psy += oy; pqy = fmaf(oy, oy, pqy);
        }
    }
    // block reduce (h==0 lanes carry the values)
    if (h == 0) {
        red[w * 32 + p] = psx;
        red[128 + w * 32 + p] = psy;
        red[256 + w * 32 + p] = pqx;
        red[384 + w * 32 + p] = pqy;
    }
    __syncthreads();
    float* sp = stats_p + (blockIdx.x & 63) * 128;
    if (tid < 64) {        // channel c = tid: sum
        int c = tid, pp = c >> 1, odd = c & 1;
        float* b = red + odd * 128;
        atomicAdd(&sp[c], b[pp] + b[32 + pp] + b[64 + pp] + b[96 + pp]);
    } else if (tid < 128) {  // channel c: sumsq
        int c = tid - 64, pp = c >> 1, odd = c & 1;
        float* b = red + 256 + odd * 128;
        atomicAdd(&sp[64 + c], b[pp] + b[32 + pp] + b[64 + pp] + b[96 + pp]);
    }
}

// Elementwise BN+ReLU apply. Prologue: reduce stats_p[64][128] (32KB,
// L2-hot) -> bnprep scale/shift.
__global__ __launch_bounds__(256) void k_bn(const unsigned* __restrict__ yagg,
                                            const float* __restrict__ stats_p,
                                            const float* __restrict__ gamma,
                                            const float* __restrict__ beta,
                                            float* __restrict__ out, int N,
                                            float invN) {
    __shared__ float ssl[128];
    int t = threadIdx.x;
    if (t < 64) {
        float s = 0.f, q = 0.f;
        for (int j = 0; j < 64; j++) {
            s += stats_p[j * 128 + t];
            q += stats_p[j * 128 + 64 + t];
        }
        float mean = s * invN;
        float var = q * invN - mean * mean;  // biased var
        float sc = gamma[t] * rsqrtf(var + BN_EPS);
        ssl[t] = sc;
        ssl[64 + t] = beta[t] - mean * sc;
    }
    __syncthreads();
    int total = N * 32;
    for (int i = blockIdx.x * 256 + t; i < total; i += gridDim.x * 256) {
        unsigned u = yagg[i];
        int p = i & 31;
        float2 o;
        o.x = fmaxf(fmaf(bf2f(u & 0xFFFFu), ssl[2 * p], ssl[64 + 2 * p]), 0.f);
        o.y = fmaxf(fmaf(bf2f(u >> 16), ssl[2 * p + 1], ssl[64 + 2 * p + 1]), 0.f);
        ((float2*)out)[i] = o;
    }
}

extern "C" void kernel_launch(void* const* d_in, const int* in_sizes, int n_in,
                              void* d_out, int out_size, void* d_ws, size_t ws_size,
                              hipStream_t stream) {
    const float* x = (const float*)d_in[0];
    const int* ei = (const int*)d_in[1];
    const float* W = (const float*)d_in[2];
    // d_in[3] = bias: cancels inside BatchNorm, unused.
    const float* gamma = (const float*)d_in[4];
    const float* beta = (const float*)d_in[5];
    float* out = (float*)d_out;

    const int N = in_sizes[0] / 64;
    const int E = in_sizes[1] / 2;
    const int* src = ei;
    const int* dst = ei + E;
    const int SUB = (N + 127) >> 7;        // 782 sub-buckets of 128 nodes
    // Per-sub-bucket count ~ Binomial(E, 128/N): mean 2049, sigma 45.
    // CAP2=3072 = mean + 22.6 sigma -> overflow impossible.

    char* ws = (char*)d_ws;
    size_t o = 0;
    int* cnt2 = (int*)(ws + o); o += 4096;         // SUB ints
    float* stats_p = (float*)(ws + o); o += 32768; // [64][128] partials
    // one memset covers cnt2 + stats_p (contiguous 36864 B)
    int* deg = (int*)(ws + o); o += (size_t)4 * N;
    int* offs = (int*)(ws + o); o += (size_t)4 * N;
    float* dinv = (float*)(ws + o); o += (size_t)4 * N;
    unsigned short* yb = (unsigned short*)(ws + o); o += (size_t)128 * (N + 1);
    unsigned* yagg = (unsigned*)(ws + o); o += (size_t)128 * N;
    unsigned* binned = (unsigned*)(ws + o); o += (size_t)4 * SUB * CAP2;
    // csr aliases binned: k_csr scatters in place (window staged in LDS).

    hipMemsetAsync(ws, 0, 36864, stream);

    const int EB = (E + 4095) / 4096;      // 391 binning blocks
    const int PB = (N + 63) / 64;          // 1563 projection blocks
    k_pre<<<EB + PB, 256, 0, stream>>>(src, dst, x, W, cnt2, binned, yb,
                                       (unsigned*)(yb + (size_t)N * 64),
                                       E, SUB, EB, N);
    k_csr<<<SUB, 256, 0, stream>>>(cnt2, binned, deg, dinv, offs,
                                   (unsigned*)yb, N);
    k_agg<<<2048, 256, 0, stream>>>(offs, deg, (const int*)binned, yb, dinv,
                                    yagg, stats_p, N);
    k_bn<<<1024, 256, 0, stream>>>(yagg, stats_p, gamma, beta, out, N,
                                   1.0f / (float)N);
}

// Round 15
// 177.224 us; speedup vs baseline: 1.1493x; 1.0338x over previous
//
#include <hip/hip_runtime.h>
#include <hip/hip_bf16.h>

#ifndef BN_EPS
#define BN_EPS 1e-5f
#endif

// ---------------------------------------------------------------------------
// N=100000, C=64, E=1600000.
// R26: R25 + proj inner loop re-packed for ds_read_b128 (3x fewer LDS ops).
//   R25 post-mortem: k_pre 45us at VALUBusy 50%; occupancy (34.5%) below the
//   LDS cap -> co-residency no longer binding. The stall: proj inner loop
//   issues 3 LDS ops per 4 FMAs (2 uniform b32 row reads + 1 b64 W read).
//   Fix: rows read as uniform uint4 (8 bf16/read); W staged as float4
//   Wq[16][64] (Wq[kh][c] = W[4kh..4kh+3][c]) -> 4 b128 per 16 FMAs.
//   k-summation order unchanged -> bit-identical output (absmax 0.03125).
//   Also: k_csr scale loop vectorized to uint4.
//   Bin path / k_agg / k_bn byte-identical to R25 (183.2us, passed).
// 5 dispatches: memset(cnt2+stats_p), pre(bin||proj), csr(+scale),
// agg(+stats), bn. bias cancels inside BatchNorm, skipped.
// ---------------------------------------------------------------------------

#define CAP2 3072  // per-sub-bucket slack capacity (mean 2049, sigma 45)

__device__ __forceinline__ unsigned short f2bf(float f) {
    unsigned u = __float_as_uint(f);
    u += 0x7FFF + ((u >> 16) & 1);  // round-to-nearest-even
    return (unsigned short)(u >> 16);
}
__device__ __forceinline__ float bf2f(unsigned v) {
    return __uint_as_float(v << 16);
}
__device__ __forceinline__ unsigned scale2(unsigned u, float dn) {
    unsigned lo = f2bf(bf2f(u & 0xFFFFu) * dn);
    unsigned hi = f2bf(bf2f(u >> 16) * dn);
    return lo | (hi << 16);
}

// Blocks [0, EB): direct 782-bucket binning (CHUNK=4096, hint-search flush).
// Blocks [EB, EB+PB): 64-row projection tiles y' = bf16(x@W), b128 operands.
// LDS union: bin 26752B, proj 24576B.
// Block 0 also zeroes the y zero row.
__global__ __launch_bounds__(256) void k_pre(const int* __restrict__ src,
                                             const int* __restrict__ dst,
                                             const float* __restrict__ x,
                                             const float* __restrict__ W,
                                             int* __restrict__ cnt2,
                                             unsigned* __restrict__ binned,
                                             unsigned short* __restrict__ yb,
                                             unsigned* __restrict__ ybz,
                                             int E, int SUB, int EB, int N) {
    __shared__ __align__(16) char smem[26752];
    int tid = threadIdx.x;
    int bid = blockIdx.x;
    if (bid == 0) {
        if (tid < 32) ybz[tid] = 0u;
    }
    if (bid >= EB) {
        // ---- projection path: y'[n] = bf16(x[n] @ W), 64-row tile ----
        unsigned* tile = (unsigned*)smem;            // 64*32 u32 = 8KB
        float4* Wq = (float4*)(smem + 8192);         // [16][64] f4 = 16KB
        int lane = tid & 63;
        int w = tid >> 6;
        int r0 = (bid - EB) * 64;
        const float4* gp = (const float4*)(x + (size_t)r0 * 64);
#pragma unroll
        for (int i = 0; i < 4; i++) {
            int idx = tid + 256 * i;        // row = idx>>4, c4 = idx&15
            int n = r0 + (idx >> 4);
            float4 v = {0.f, 0.f, 0.f, 0.f};
            if (n < N) v = gp[idx];
            unsigned lo = (unsigned)f2bf(v.x) | ((unsigned)f2bf(v.y) << 16);
            unsigned hi = (unsigned)f2bf(v.z) | ((unsigned)f2bf(v.w) << 16);
            tile[(idx >> 4) * 32 + (idx & 15) * 2] = lo;
            tile[(idx >> 4) * 32 + (idx & 15) * 2 + 1] = hi;
        }
        // stage W as quads: Wq[kh*64+c] = (W[4kh][c],...,W[4kh+3][c])
#pragma unroll
        for (int i = 0; i < 4; i++) {
            int idx = tid + 256 * i;        // kh = idx>>6, c = idx&63
            int kh = idx >> 6, c = idx & 63;
            float4 w4;
            w4.x = W[(4 * kh + 0) * 64 + c];
            w4.y = W[(4 * kh + 1) * 64 + c];
            w4.z = W[(4 * kh + 2) * 64 + c];
            w4.w = W[(4 * kh + 3) * 64 + c];
            Wq[idx] = w4;
        }
        __syncthreads();
#pragma unroll
        for (int rr = 0; rr < 16; rr += 2) {
            int lr0 = w * 16 + rr;
            int n0 = r0 + lr0;
            if (n0 >= N) break;
            const uint4* row0 = (const uint4*)(tile + lr0 * 32);
            const uint4* row1 = (const uint4*)(tile + lr0 * 32 + 32);
            float o0 = 0.f, o1 = 0.f;
#pragma unroll
            for (int kq = 0; kq < 8; kq++) {  // k = 8kq .. 8kq+7
                uint4 u0 = row0[kq];          // uniform b128 (broadcast)
                uint4 u1 = row1[kq];
                float4 wa = Wq[(2 * kq) * 64 + lane];      // W[8kq..8kq+3]
                float4 wb = Wq[(2 * kq + 1) * 64 + lane];  // W[8kq+4..8kq+7]
                o0 = fmaf(bf2f(u0.x & 0xFFFFu), wa.x, o0);
                o0 = fmaf(bf2f(u0.x >> 16), wa.y, o0);
                o0 = fmaf(bf2f(u0.y & 0xFFFFu), wa.z, o0);
                o0 = fmaf(bf2f(u0.y >> 16), wa.w, o0);
                o0 = fmaf(bf2f(u0.z & 0xFFFFu), wb.x, o0);
                o0 = fmaf(bf2f(u0.z >> 16), wb.y, o0);
                o0 = fmaf(bf2f(u0.w & 0xFFFFu), wb.z, o0);
                o0 = fmaf(bf2f(u0.w >> 16), wb.w, o0);
                o1 = fmaf(bf2f(u1.x & 0xFFFFu), wa.x, o1);
                o1 = fmaf(bf2f(u1.x >> 16), wa.y, o1);
                o1 = fmaf(bf2f(u1.y & 0xFFFFu), wa.z, o1);
                o1 = fmaf(bf2f(u1.y >> 16), wa.w, o1);
                o1 = fmaf(bf2f(u1.z & 0xFFFFu), wb.x, o1);
                o1 = fmaf(bf2f(u1.z >> 16), wb.y, o1);
                o1 = fmaf(bf2f(u1.w & 0xFFFFu), wb.z, o1);
                o1 = fmaf(bf2f(u1.w >> 16), wb.w, o1);
            }
            yb[(size_t)n0 * 64 + lane] = f2bf(o0);
            if (n0 + 1 < N) yb[(size_t)(n0 + 1) * 64 + lane] = f2bf(o1);
        }
        return;
    }
    // ---- binning path (R25 body: CHUNK=4096, hint-search flush) ----
    int* h2 = (int*)smem;                              // 1024 ints
    int* gbase = (int*)(smem + 4096);                  // 784
    int* hcur = (int*)(smem + 7232);                   // 784
    unsigned* lout = (unsigned*)(smem + 10368);        // 4096 u32 -> end 26752
    int c0 = bid * 4096;
    if (c0 >= E) return;
    int cnt = min(4096, E - c0);
    for (int i = tid; i < 1024; i += 256) h2[i] = 0;
    __syncthreads();
    for (int i = tid; i < cnt; i += 256)
        atomicAdd(&h2[dst[c0 + i] >> 7], 1);
    __syncthreads();
    // inclusive scan of h2[0..1024) with 256 threads (read-all/write-all)
    for (int off = 1; off < 1024; off <<= 1) {
        int t0 = tid, t1 = tid + 256, t2 = tid + 512, t3 = tid + 768;
        int a0 = (t0 >= off) ? h2[t0 - off] : 0;
        int a1 = (t1 >= off) ? h2[t1 - off] : 0;
        int a2 = (t2 >= off) ? h2[t2 - off] : 0;
        int a3 = (t3 >= off) ? h2[t3 - off] : 0;
        __syncthreads();
        h2[t0] += a0; h2[t1] += a1; h2[t2] += a2; h2[t3] += a3;
        __syncthreads();
    }
    // reserve global space per nonempty sub-bucket; init local cursors
    for (int s2 = tid; s2 < SUB; s2 += 256) {
        int prev = s2 ? h2[s2 - 1] : 0;
        int v = h2[s2] - prev;
        hcur[s2] = prev;
        if (v > 0) gbase[s2] = atomicAdd(&cnt2[s2], v);
    }
    __syncthreads();
    // pack into LDS grouped by sub-bucket; top byte = sb low 8 bits (hint)
    for (int i = tid; i < cnt; i += 256) {
        int d = dst[c0 + i];
        int s = src[c0 + i];
        int sb = d >> 7;
        unsigned packed = (unsigned)s | ((unsigned)(d & 127) << 17) |
                          ((unsigned)(sb & 255) << 24);
        int p = atomicAdd(&hcur[sb], 1);
        lout[p] = packed;
    }
    __syncthreads();
    // grouped flush: bucket of position i recovered from h2 ranges using the
    // hint -- candidates are hint+256k (<=4, exactly one contains i).
    for (int i = tid; i < cnt; i += 256) {
        unsigned v = lout[i];
        int sb = v >> 24;  // start at hint
        int hx = 0;
        for (; sb < SUB; sb += 256) {
            int lo = sb ? h2[sb - 1] : 0;
            if (i >= lo && i < h2[sb]) { hx = lo; break; }
        }
        binned[(size_t)sb * CAP2 + gbase[sb] + (i - hx)] = v & 0xFFFFFFu;
    }
}

// One block per 128-node sub-bucket: stage window in LDS, LDS histogram ->
// deg/dinv/offs, scatter csr IN PLACE, then scale this block's 128 y' rows
// in place (uint4): y[n] = bf16(dinv[n] * y'[n]).
__global__ __launch_bounds__(256) void k_csr(const int* __restrict__ cnt2,
                                             unsigned* __restrict__ binned,
                                             int* __restrict__ deg,
                                             float* __restrict__ dinv,
                                             int* __restrict__ offs,
                                             unsigned* __restrict__ ybw,
                                             int N) {
    __shared__ int hist[128], lbase[128], lcur[128];
    __shared__ float sdv[128];
    __shared__ unsigned win[CAP2];
    int s = blockIdx.x;
    int tid = threadIdx.x;
    int cnt = cnt2[s];
    unsigned* bb = binned + (size_t)s * CAP2;
    for (int j = tid; j < cnt; j += 256) win[j] = bb[j];
    if (tid < 128) { hist[tid] = 0; lcur[tid] = 0; }
    __syncthreads();
    for (int j = tid; j < cnt; j += 256)
        atomicAdd(&hist[win[j] >> 17], 1);
    __syncthreads();
    if (tid == 0) {
        int acc = 0;
        for (int k = 0; k < 128; k++) { lbase[k] = acc; acc += hist[k]; }
    }
    __syncthreads();
    if (tid < 128) {  // deg / dinv / offs for this sub-bucket's 128 nodes
        int n = (s << 7) + tid;
        float dn = rsqrtf((float)(hist[tid] + 1));  // +1 = self-loop
        sdv[tid] = dn;
        if (n < N) {
            deg[n] = hist[tid];
            dinv[n] = dn;
            offs[n] = s * CAP2 + lbase[tid];
        }
    }
    __syncthreads();
    // in-place scatter: reads fully staged in win, writes node-ordered
    for (int j = tid; j < cnt; j += 256) {
        unsigned e = win[j];
        int ld = e >> 17;
        bb[lbase[ld] + atomicAdd(&lcur[ld], 1)] = e & 0x1FFFFu;
    }
    // scale this block's 128 rows in place: y = bf16(dinv * y'), uint4
    uint4* yrow4 = (uint4*)(ybw + (size_t)(s << 7) * 32);  // 128 rows x 8 u4
    for (int i = tid; i < 1024; i += 256) {
        int n = (s << 7) + (i >> 3);
        if (n < N) {
            float dn = sdv[i >> 3];
            uint4 u = yrow4[i];
            u.x = scale2(u.x, dn);
            u.y = scale2(u.y, dn);
            u.z = scale2(u.z, dn);
            u.w = scale2(u.w, dn);
            yrow4[i] = u;
        }
    }
}

// Wave per node, aggregation in y-space (R15 body). BN stats fused with
// 64-way-spread atomics (R21 proven).
__global__ __launch_bounds__(256) void k_agg(const int* __restrict__ offs,
                                             const int* __restrict__ deg,
                                             const int* __restrict__ csr,
                                             const unsigned short* __restrict__ yb,
                                             const float* __restrict__ dinv,
                                             unsigned* __restrict__ yagg,
                                             float* __restrict__ stats_p, int N) {
    __shared__ float red[512];  // [4: psx psy pqx pqy][4 waves][32 p]
    int tid = threadIdx.x;
    int lane = tid & 63;
    int p = lane & 31;   // channel pair (channels 2p, 2p+1)
    int h = lane >> 5;   // half: which edge of a pair this lane gathers
    int w = tid >> 6;
    int wid = (blockIdx.x * 256 + tid) >> 6;
    int nw = (gridDim.x * 256) >> 6;
    const unsigned* xw = (const unsigned*)yb;

    float psx = 0.f, psy = 0.f, pqx = 0.f, pqy = 0.f;
    for (int n = wid; n < N; n += nw) {
        float dn = dinv[n];
        unsigned sv = xw[(size_t)n * 32 + p];  // self row (pre-scaled)
        float accx = (h == 0) ? bf2f(sv & 0xFFFFu) : 0.f;
        float accy = (h == 0) ? bf2f(sv >> 16) : 0.f;
        int j0 = offs[n];
        int j1 = j0 + deg[n];
        for (int jb = j0; jb < j1; jb += 64) {
            int cnt = min(64, j1 - jb);
            int idx = N;  // zero row for overshoot lanes
            if (lane < cnt) idx = csr[jb + lane];
            for (int j = 0; j < cnt; j += 16) {
                int s0 = __shfl(idx, j + 0 + h),  s1 = __shfl(idx, j + 2 + h);
                int s2 = __shfl(idx, j + 4 + h),  s3 = __shfl(idx, j + 6 + h);
                int s4 = __shfl(idx, j + 8 + h),  s5 = __shfl(idx, j + 10 + h);
                int s6 = __shfl(idx, j + 12 + h), s7 = __shfl(idx, j + 14 + h);
                unsigned v0 = xw[(size_t)s0 * 32 + p];
                unsigned v1 = xw[(size_t)s1 * 32 + p];
                unsigned v2 = xw[(size_t)s2 * 32 + p];
                unsigned v3 = xw[(size_t)s3 * 32 + p];
                unsigned v4 = xw[(size_t)s4 * 32 + p];
                unsigned v5 = xw[(size_t)s5 * 32 + p];
                unsigned v6 = xw[(size_t)s6 * 32 + p];
                unsigned v7 = xw[(size_t)s7 * 32 + p];
                accx += bf2f(v0 & 0xFFFFu); accy += bf2f(v0 >> 16);
                accx += bf2f(v1 & 0xFFFFu); accy += bf2f(v1 >> 16);
                accx += bf2f(v2 & 0xFFFFu); accy += bf2f(v2 >> 16);
                accx += bf2f(v3 & 0xFFFFu); accy += bf2f(v3 >> 16);
                accx += bf2f(v4 & 0xFFFFu); accy += bf2f(v4 >> 16);
                accx += bf2f(v5 & 0xFFFFu); accy += bf2f(v5 >> 16);
                accx += bf2f(v6 & 0xFFFFu); accy += bf2f(v6 >> 16);
                accx += bf2f(v7 & 0xFFFFu); accy += bf2f(v7 >> 16);
            }
        }
        accx += __shfl_xor(accx, 32);
        accy += __shfl_xor(accy, 32);
        float ox = accx * dn, oy = accy * dn;  // pre-BN outputs
        if (h == 0) {
            unsigned o = (unsigned)f2bf(ox) | ((unsigned)f2bf(oy) << 16);
            yagg[(size_t)n * 32 + p] = o;
            psx += ox; pqx = fmaf(ox, ox, pqx);
            psy += oy; pqy = fmaf(oy, oy, pqy);
        }
    }
    // block reduce (h==0 lanes carry the values)
    if (h == 0) {
        red[w * 32 + p] = psx;
        red[128 + w * 32 + p] = psy;
        red[256 + w * 32 + p] = pqx;
        red[384 + w * 32 + p] = pqy;
    }
    __syncthreads();
    float* sp = stats_p + (blockIdx.x & 63) * 128;
    if (tid < 64) {        // channel c = tid: sum
        int c = tid, pp = c >> 1, odd = c & 1;
        float* b = red + odd * 128;
        atomicAdd(&sp[c], b[pp] + b[32 + pp] + b[64 + pp] + b[96 + pp]);
    } else if (tid < 128) {  // channel c: sumsq
        int c = tid - 64, pp = c >> 1, odd = c & 1;
        float* b = red + 256 + odd * 128;
        atomicAdd(&sp[64 + c], b[pp] + b[32 + pp] + b[64 + pp] + b[96 + pp]);
    }
}

// Elementwise BN+ReLU apply. Prologue: reduce stats_p[64][128] (32KB,
// L2-hot) -> bnprep scale/shift.
__global__ __launch_bounds__(256) void k_bn(const unsigned* __restrict__ yagg,
                                            const float* __restrict__ stats_p,
                                            const float* __restrict__ gamma,
                                            const float* __restrict__ beta,
                                            float* __restrict__ out, int N,
                                            float invN) {
    __shared__ float ssl[128];
    int t = threadIdx.x;
    if (t < 64) {
        float s = 0.f, q = 0.f;
        for (int j = 0; j < 64; j++) {
            s += stats_p[j * 128 + t];
            q += stats_p[j * 128 + 64 + t];
        }
        float mean = s * invN;
        float var = q * invN - mean * mean;  // biased var
        float sc = gamma[t] * rsqrtf(var + BN_EPS);
        ssl[t] = sc;
        ssl[64 + t] = beta[t] - mean * sc;
    }
    __syncthreads();
    int total = N * 32;
    for (int i = blockIdx.x * 256 + t; i < total; i += gridDim.x * 256) {
        unsigned u = yagg[i];
        int p = i & 31;
        float2 o;
        o.x = fmaxf(fmaf(bf2f(u & 0xFFFFu), ssl[2 * p], ssl[64 + 2 * p]), 0.f);
        o.y = fmaxf(fmaf(bf2f(u >> 16), ssl[2 * p + 1], ssl[64 + 2 * p + 1]), 0.f);
        ((float2*)out)[i] = o;
    }
}

extern "C" void kernel_launch(void* const* d_in, const int* in_sizes, int n_in,
                              void* d_out, int out_size, void* d_ws, size_t ws_size,
                              hipStream_t stream) {
    const float* x = (const float*)d_in[0];
    const int* ei = (const int*)d_in[1];
    const float* W = (const float*)d_in[2];
    // d_in[3] = bias: cancels inside BatchNorm, unused.
    const float* gamma = (const float*)d_in[4];
    const float* beta = (const float*)d_in[5];
    float* out = (float*)d_out;

    const int N = in_sizes[0] / 64;
    const int E = in_sizes[1] / 2;
    const int* src = ei;
    const int* dst = ei + E;
    const int SUB = (N + 127) >> 7;        // 782 sub-buckets of 128 nodes
    // Per-sub-bucket count ~ Binomial(E, 128/N): mean 2049, sigma 45.
    // CAP2=3072 = mean + 22.6 sigma -> overflow impossible.

    char* ws = (char*)d_ws;
    size_t o = 0;
    int* cnt2 = (int*)(ws + o); o += 4096;         // SUB ints
    float* stats_p = (float*)(ws + o); o += 32768; // [64][128] partials
    // one memset covers cnt2 + stats_p (contiguous 36864 B)
    int* deg = (int*)(ws + o); o += (size_t)4 * N;
    int* offs = (int*)(ws + o); o += (size_t)4 * N;
    float* dinv = (float*)(ws + o); o += (size_t)4 * N;
    unsigned short* yb = (unsigned short*)(ws + o); o += (size_t)128 * (N + 1);
    unsigned* yagg = (unsigned*)(ws + o); o += (size_t)128 * N;
    unsigned* binned = (unsigned*)(ws + o); o += (size_t)4 * SUB * CAP2;
    // csr aliases binned: k_csr scatters in place (window staged in LDS).

    hipMemsetAsync(ws, 0, 36864, stream);

    const int EB = (E + 4095) / 4096;      // 391 binning blocks
    const int PB = (N + 63) / 64;          // 1563 projection blocks
    k_pre<<<EB + PB, 256, 0, stream>>>(src, dst, x, W, cnt2, binned, yb,
                                       (unsigned*)(yb + (size_t)N * 64),
                                       E, SUB, EB, N);
    k_csr<<<SUB, 256, 0, stream>>>(cnt2, binned, deg, dinv, offs,
                                   (unsigned*)yb, N);
    k_agg<<<2048, 256, 0, stream>>>(offs, deg, (const int*)binned, yb, dinv,
                                    yagg, stats_p, N);
    k_bn<<<1024, 256, 0, stream>>>(yagg, stats_p, gamma, beta, out, N,
                                   1.0f / (float)N);
}